// Round 15
// baseline (226.795 us; speedup 1.0000x reference)
//
#include <hip/hip_runtime.h>

#define HW     16384
#define CIN    512
#define KCH    256
#define NKEY   19
#define NKP    32
#define NBATCH 8

typedef __attribute__((ext_vector_type(8))) short s16x8;
typedef __attribute__((ext_vector_type(4))) short s16x4;
typedef __attribute__((ext_vector_type(4))) float f32x4;
typedef __attribute__((ext_vector_type(2))) float f32x2;

// HW f32->bf16 (RNE): compiles to v_cvt_pk_bf16_f32 on gfx950
__device__ __forceinline__ short f2bf(float f) {
  __bf16 h = (__bf16)f;
  return __builtin_bit_cast(short, h);
}

// Barrier that does NOT drain vmcnt: lgkmcnt(0) (my ds ops done) + s_barrier.
// In-flight global prefetch loads survive across it (T4).
#define BARRIER_LG() do { \
    asm volatile("s_waitcnt lgkmcnt(0)" ::: "memory"); \
    __builtin_amdgcn_s_barrier(); \
    asm volatile("" ::: "memory"); \
  } while (0)

// ---------------- prep A: fold W1/W2/biases (blocks 0..771); GEMM1/3 (blocks 772+) ----
__global__ __launch_bounds__(256) void kprepA(
    const float* __restrict__ proxy,
    const float* __restrict__ w_p1, const float* __restrict__ w_p2,
    const float* __restrict__ p1g, const float* __restrict__ p1b,
    const float* __restrict__ p1m, const float* __restrict__ p1v,
    const float* __restrict__ p2g, const float* __restrict__ p2b,
    const float* __restrict__ p2m, const float* __restrict__ p2v,
    const float* __restrict__ ug,  const float* __restrict__ ub,
    const float* __restrict__ um,  const float* __restrict__ uvv,
    const float* __restrict__ w_o1, const float* __restrict__ w_d,
    const float* __restrict__ o1g, const float* __restrict__ o1b,
    const float* __restrict__ o1m, const float* __restrict__ o1v,
    const float* __restrict__ dg,  const float* __restrict__ db,
    const float* __restrict__ dm,  const float* __restrict__ dv,
    short* __restrict__ W1L, short* __restrict__ W2L,
    float* __restrict__ b1, float* __restrict__ b2, float* __restrict__ bu,
    float* __restrict__ t_o1g, float* __restrict__ vmatg)
{
  __shared__ char PB[32 * 1024];          // [32key][512c] bf16, byte ^ ((key&7)<<4)
  const int tid = threadIdx.x;
  if (blockIdx.x < 772) {
    int t = blockIdx.x * 256 + tid;
    if (t < 131072) {
      int kf = t >> 13, rem = t & 8191, tt = rem >> 9, e512 = rem & 511;
      int l = e512 >> 3, e = e512 & 7;
      int m = tt * 16 + (l & 15);
      int kcol = kf * 32 + (l >> 4) * 8 + e;
      float inv = p1g[m] * rsqrtf(p1v[m] + 1e-5f);
      W1L[t] = f2bf(inv * w_p1[(size_t)m * CIN + kcol]);
    } else if (t < 196608) {
      int u = t - 131072;
      int kf = u >> 13, rem = u & 8191, tt = rem >> 9, e512 = rem & 511;
      int l = e512 >> 3, e = e512 & 7;
      int m = tt * 16 + (l & 15);
      int kcol = kf * 32 + (l >> 4) * 8 + e;
      float inv = p2g[m] * rsqrtf(p2v[m] + 1e-5f);
      W2L[u] = f2bf(inv * w_p2[(size_t)m * KCH + kcol]);
    } else if (t < 196608 + 256) {
      int o = t - 196608;
      float inv = p1g[o] * rsqrtf(p1v[o] + 1e-5f);
      b1[o] = p1b[o] - p1m[o] * inv;
    } else if (t < 196608 + 512) {
      int o = t - 196608 - 256;
      float inv = p2g[o] * rsqrtf(p2v[o] + 1e-5f);
      b2[o] = p2b[o] - p2m[o] * inv;
    } else if (t < 196608 + 1024) {
      int o = t - 196608 - 512;
      float inv = ug[o] * rsqrtf(uvv[o] + 1e-5f);
      bu[o] = ub[o] - um[o] * inv;
    }
    return;
  }
  int bid = blockIdx.x - 772;            // [0,64)
  int sel = bid >> 5;
  int r5  = bid & 31;
  int n   = r5 >> 2;
  int mbase = (r5 & 3) << 6;

  for (int j = 0; j < 8; ++j) *(s16x8*)(PB + (tid + j * 256) * 16) = (s16x8)0;
  __syncthreads();
  const float* pn = proxy + (size_t)n * CIN * NKEY;
  for (int e = tid; e < CIN * NKEY; e += 256) {
    int c = e / NKEY, k = e - c * NKEY;
    *(short*)(PB + k * 1024 + ((c << 1) ^ ((k & 7) << 4))) = f2bf(pn[e]);
  }
  __syncthreads();

  const int w = tid >> 6, lane = tid & 63, g = lane >> 4, i = lane & 15;
  const float* W  = sel ? w_d : w_o1;
  const float* gg = sel ? dg : o1g;
  const float* bb = sel ? db : o1b;
  const float* mm = sel ? dm : o1m;
  const float* vv = sel ? dv : o1v;
  f32x4 acc2[2];
  acc2[0] = (f32x4)0.f; acc2[1] = (f32x4)0.f;
  const int arow = mbase + w * 16 + i;
#pragma unroll 1
  for (int kf = 0; kf < 16; ++kf) {
    const float* wp = W + (size_t)arow * CIN + kf * 32 + g * 8;
    f32x4 a0 = *(const f32x4*)wp, a1 = *(const f32x4*)(wp + 4);
    s16x8 af;
#pragma unroll
    for (int e = 0; e < 4; ++e) { af[e] = f2bf(a0[e]); af[e + 4] = f2bf(a1[e]); }
#pragma unroll
    for (int nj = 0; nj < 2; ++nj) {
      int key = nj * 16 + i;
      s16x8 bf = *(const s16x8*)(PB + key * 1024 + ((kf * 64 + g * 16) ^ ((key & 7) << 4)));
      acc2[nj] = __builtin_amdgcn_mfma_f32_16x16x32_bf16(af, bf, acc2[nj], 0, 0, 0);
    }
  }
  float* dst = (sel ? vmatg : t_o1g) + (size_t)n * 8192;
#pragma unroll
  for (int r = 0; r < 4; ++r) {
    int o = mbase + w * 16 + g * 4 + r;
    float inv = gg[o] * rsqrtf(vv[o] + 1e-5f);
    float beta = bb[o] - mm[o] * inv;
#pragma unroll
    for (int nj = 0; nj < 2; ++nj) {
      int key = nj * 16 + i;
      dst[key * 256 + o] = fmaxf(acc2[nj][r] * inv + beta, 0.f);
    }
  }
}

// ---------------- prep B: GEMM2 -> KmL (frag layout), GEMM4 -> WuL (frag layout) ------
__global__ __launch_bounds__(256) void kprepB(
    const float* __restrict__ w_o2, const float* __restrict__ w_u,
    const float* __restrict__ o2g, const float* __restrict__ o2b,
    const float* __restrict__ o2m, const float* __restrict__ o2v,
    const float* __restrict__ ug,  const float* __restrict__ uvv,
    const float* __restrict__ t_o1g, const float* __restrict__ vmatg,
    short* __restrict__ KmL, short* __restrict__ WuL)
{
  __shared__ char TB[32 * 512];           // [32key][256o] bf16, byte ^ ((key&7)<<4)
  const int tid = threadIdx.x;
  const int isKm = (blockIdx.x < 32);
  int n, mbase;
  const float* src;
  if (isKm) { n = blockIdx.x >> 2; mbase = (blockIdx.x & 3) << 6; src = t_o1g; }
  else { int b2_ = blockIdx.x - 32; n = b2_ >> 3; mbase = (b2_ & 7) << 6; src = vmatg; }
  const float* sn = src + (size_t)n * 8192;
  for (int j = 0; j < 32; ++j) {
    int idx = tid + j * 256;
    int key = idx >> 8, o = idx & 255;
    *(short*)(TB + key * 512 + ((o << 1) ^ ((key & 7) << 4))) = f2bf(sn[idx]);
  }
  __syncthreads();

  const int w = tid >> 6, lane = tid & 63, g = lane >> 4, i = lane & 15;
  const float* W = isKm ? w_o2 : w_u;
  f32x4 acc2[2];
  acc2[0] = (f32x4)0.f; acc2[1] = (f32x4)0.f;
  const int arow = mbase + w * 16 + i;
#pragma unroll 1
  for (int kf = 0; kf < 8; ++kf) {
    const float* wp = W + (size_t)arow * KCH + kf * 32 + g * 8;
    f32x4 a0 = *(const f32x4*)wp, a1 = *(const f32x4*)(wp + 4);
    s16x8 af;
#pragma unroll
    for (int e = 0; e < 4; ++e) { af[e] = f2bf(a0[e]); af[e + 4] = f2bf(a1[e]); }
#pragma unroll
    for (int nj = 0; nj < 2; ++nj) {
      int key = nj * 16 + i;
      s16x8 bf = *(const s16x8*)(TB + key * 512 + ((kf * 64 + g * 16) ^ ((key & 7) << 4)));
      acc2[nj] = __builtin_amdgcn_mfma_f32_16x16x32_bf16(af, bf, acc2[nj], 0, 0, 0);
    }
  }
  if (isKm) {
    short* Kn = KmL + (size_t)n * 8192;
#pragma unroll
    for (int r = 0; r < 4; ++r) {
      int o2 = mbase + w * 16 + g * 4 + r;
      float inv = o2g[o2] * rsqrtf(o2v[o2] + 1e-5f);
      float beta = o2b[o2] - o2m[o2] * inv;
#pragma unroll
      for (int nj = 0; nj < 2; ++nj) {
        float val = fmaxf(acc2[nj][r] * inv + beta, 0.f) * 0.0625f;
        Kn[((o2 >> 5) * 2 + nj) * 512 + (((o2 >> 3) & 3) * 16 + i) * 8 + (o2 & 7)] = f2bf(val);
      }
    }
  } else {
    short* Wn = WuL + (size_t)n * 16384;
#pragma unroll
    for (int r = 0; r < 4; ++r) {
      int c = mbase + w * 16 + g * 4 + r;
      float inv = ug[c] * rsqrtf(uvv[c] + 1e-5f);
#pragma unroll
      for (int nj = 0; nj < 2; ++nj) {
        int key = nj * 16 + i;
        float val = acc2[nj][r] * inv;
        Wn[(c >> 4) * 512 + ((key >> 3) * 16 + (c & 15)) * 8 + (key & 7)] = f2bf(val);
      }
    }
  }
}

// ---------------- fused main kernel: 512 threads / 128 pixels / 64 KB LDS -------------
// Geometry 2x wider than R13: per-block 128-px tile -> 512 B HBM segments on both the
// x-read and out-write streams (was 256 B), half the stream count, half the barriers
// per pixel. Per-wave shapes identical to R9/R13 (32 px-pairs x 2 ch-octets staging,
// 2-way-free LDS banks; 32ch x 128px MFMA tile keeps acc at 64 AGPRs).
#define LOADCHUNK(R2, ck) do { \
    const float* xp = xb2 + (size_t)((ck) * 64 + ch0) * HW; \
    _Pragma("unroll") \
    for (int c = 0; c < 8; ++c) (R2)[c] = *(const f32x2*)(xp + (size_t)c * HW); \
  } while (0)

#define WRITECHUNK(R2, ck) do { \
    char* wr_ = smem + ((ck) % 3) * 16384; \
    _Pragma("unroll") \
    for (int p = 0; p < 2; ++p) { \
      int px_ = pxp + p; \
      s16x8 h; \
      _Pragma("unroll") \
      for (int c = 0; c < 8; ++c) h[c] = f2bf((R2)[c][p]); \
      *(s16x8*)(wr_ + px_ * 128 + ((ch0 << 1) ^ ((px_ & 7) << 4))) = h; \
    } \
  } while (0)

#define MFMASTEP(ck) do { \
    const char* rb_ = smem + ((ck) % 3) * 16384; \
    _Pragma("unroll") \
    for (int ks = 0; ks < 2; ++ks) { \
      s16x8 af[2], bf[8]; \
      _Pragma("unroll") \
      for (int mi = 0; mi < 2; ++mi) \
        af[mi] = *(const s16x8*)(W1L + ((((ck) * 2 + ks) * 16 + (w * 2 + mi)) << 9) + (lane << 3)); \
      _Pragma("unroll") \
      for (int ni = 0; ni < 8; ++ni) { \
        int p_ = ni * 16 + i; \
        bf[ni] = *(const s16x8*)(rb_ + p_ * 128 + (((ks * 32 + g * 8) << 1) ^ ((p_ & 7) << 4))); \
      } \
      _Pragma("unroll") \
      for (int mi = 0; mi < 2; ++mi) \
        _Pragma("unroll") \
        for (int ni = 0; ni < 8; ++ni) \
          acc[mi][ni] = __builtin_amdgcn_mfma_f32_16x16x32_bf16(af[mi], bf[ni], acc[mi][ni], 0, 0, 0); \
    } \
  } while (0)

__global__ __launch_bounds__(512, 4) void k_main(
    const float* __restrict__ x,
    const short* __restrict__ W1L, const short* __restrict__ W2L,
    const short* __restrict__ KmL, const short* __restrict__ WuL,
    const float* __restrict__ b1, const float* __restrict__ b2,
    const float* __restrict__ bu,
    float* __restrict__ out)
{
  __shared__ char smem[65536];           // ring-3 x 16KB aliased inside t1q [128][512B]
  char* t1q = smem;

  const int tid  = threadIdx.x;
  const int w    = tid >> 6;     // wave 0..7
  const int lane = tid & 63;
  const int g    = lane >> 4;
  const int i    = lane & 15;
  const int n    = blockIdx.x >> 7;
  const int l0   = (blockIdx.x & 127) << 7;

  f32x4 acc[2][8];
#pragma unroll
  for (int a_ = 0; a_ < 2; ++a_)
#pragma unroll
    for (int b_ = 0; b_ < 8; ++b_) acc[a_][b_] = (f32x4)0.f;

  // ---------------- Stage A: t1 = relu(W1' @ x + b1), M=256 N=128 K=512 ----------------
  // thread -> (px-pair P_, ch-octet O_): per-wave shape = 32 consecutive pairs x 2
  // octets (identical bank/coalescing profile to R13).
  const int P_  = (lane & 31) | ((w & 1) << 5);   // 0..63
  const int O_  = (lane >> 5) | ((w >> 1) << 1);  // 0..7
  const int pxp = P_ << 1;
  const int ch0 = O_ << 3;
  const float* xb2 = x + (size_t)n * CIN * HW + l0 + pxp;

  f32x2 RA[8], RB[8];
  LOADCHUNK(RA, 0);
  LOADCHUNK(RB, 1);
  WRITECHUNK(RA, 0);
  BARRIER_LG();

#pragma unroll
  for (int cp = 0; cp < 4; ++cp) {
    const int cka = 2 * cp, ckb = 2 * cp + 1;
    if (cka + 2 < 8) LOADCHUNK(RA, cka + 2);   // issue loads 2 chunks ahead
    WRITECHUNK(RB, ckb);                        // write chunk loaded last iter
    MFMASTEP(cka);
    BARRIER_LG();
    if (ckb + 2 < 8) LOADCHUNK(RB, ckb + 2);
    if (ckb + 1 < 8) WRITECHUNK(RA, ckb + 1);
    MFMASTEP(ckb);
    BARRIER_LG();
  }

  // epilogue A -> t1q (ring dead; all LDS reads drained at the loop's final barrier)
#pragma unroll
  for (int mi = 0; mi < 2; ++mi) {
    f32x4 bias = *(const f32x4*)(b1 + w * 32 + mi * 16 + g * 4);
#pragma unroll
    for (int ni = 0; ni < 8; ++ni) {
      int p = ni * 16 + i;
      s16x4 hh;
#pragma unroll
      for (int r = 0; r < 4; ++r) hh[r] = f2bf(fmaxf(acc[mi][ni][r] + bias[r], 0.f));
      *(s16x4*)(t1q + p * 512 + (((w * 32 + mi * 16 + g * 4) << 1) ^ ((p & 7) << 4))) = hh;
      acc[mi][ni] = (f32x4)0.f;
    }
  }
  __syncthreads();

  // ---------------- Stage B: q = relu(W2' @ t1 + b2), M=256 N=128 K=256 ----------------
#pragma unroll 2
  for (int ks = 0; ks < 8; ++ks) {
    s16x8 af[2], bf[8];
#pragma unroll
    for (int mi = 0; mi < 2; ++mi)
      af[mi] = *(const s16x8*)(W2L + (((ks * 16) + (w * 2 + mi)) << 9) + (lane << 3));
#pragma unroll
    for (int ni = 0; ni < 8; ++ni) {
      int p = ni * 16 + i;
      bf[ni] = *(const s16x8*)(t1q + p * 512 + (((ks * 32 + g * 8) << 1) ^ ((p & 7) << 4)));
    }
#pragma unroll
    for (int mi = 0; mi < 2; ++mi)
#pragma unroll
      for (int ni = 0; ni < 8; ++ni)
        acc[mi][ni] = __builtin_amdgcn_mfma_f32_16x16x32_bf16(af[mi], bf[ni], acc[mi][ni], 0, 0, 0);
  }
  __syncthreads();              // all t1 reads complete before overwrite
#pragma unroll
  for (int mi = 0; mi < 2; ++mi) {
    f32x4 bias = *(const f32x4*)(b2 + w * 32 + mi * 16 + g * 4);
#pragma unroll
    for (int ni = 0; ni < 8; ++ni) {
      int p = ni * 16 + i;
      s16x4 hh;
#pragma unroll
      for (int r = 0; r < 4; ++r) hh[r] = f2bf(fmaxf(acc[mi][ni][r] + bias[r], 0.f));
      *(s16x4*)(t1q + p * 512 + (((w * 32 + mi * 16 + g * 4) << 1) ^ ((p & 7) << 4))) = hh;
    }
  }
  __syncthreads();

  // ---------------- Stage S: simT = K_scaled @ q, softmax over k<19 --------------------
  f32x4 as_[2];
  as_[0] = (f32x4)0.f; as_[1] = (f32x4)0.f;
  const short* Kn = KmL + (size_t)n * 8192;
  const int ps = (w << 4) | i;          // this lane's pixel 0..127
  const int psw = (ps & 7) << 4;
#pragma unroll
  for (int ks = 0; ks < 8; ++ks) {
    s16x8 bq = *(const s16x8*)(t1q + ps * 512 + (((ks * 32 + g * 8) << 1) ^ psw));
#pragma unroll
    for (int mi = 0; mi < 2; ++mi) {
      s16x8 ak = *(const s16x8*)(Kn + (((ks * 2 + mi)) << 9) + (lane << 3));
      as_[mi] = __builtin_amdgcn_mfma_f32_16x16x32_bf16(ak, bq, as_[mi], 0, 0, 0);
    }
  }
  float mx = -1e30f;
#pragma unroll
  for (int mi = 0; mi < 2; ++mi)
#pragma unroll
    for (int r = 0; r < 4; ++r) {
      int k = mi * 16 + g * 4 + r;
      if (k < NKEY) mx = fmaxf(mx, as_[mi][r]);
    }
  mx = fmaxf(mx, __shfl_xor(mx, 16, 64));
  mx = fmaxf(mx, __shfl_xor(mx, 32, 64));
  float e[2][4];
  float sum = 0.f;
#pragma unroll
  for (int mi = 0; mi < 2; ++mi)
#pragma unroll
    for (int r = 0; r < 4; ++r) {
      int k = mi * 16 + g * 4 + r;
      float t = (k < NKEY) ? __expf(as_[mi][r] - mx) : 0.f;
      e[mi][r] = t;
      sum += t;
    }
  sum += __shfl_xor(sum, 16, 64);
  sum += __shfl_xor(sum, 32, 64);
  float rs = 1.f / sum;
  __syncthreads();                      // all t1q reads done before P overwrites it
  char* P = smem;                       // [128p][32k] bf16, swizzle (p&3)<<4 (8 KB)
#pragma unroll
  for (int mi = 0; mi < 2; ++mi) {
    s16x4 hh;
#pragma unroll
    for (int r = 0; r < 4; ++r) hh[r] = f2bf(e[mi][r] * rs);
    *(s16x4*)(P + ps * 64 + (((mi * 16 + g * 4) << 1) ^ ((ps & 3) << 4))) = hh;
  }
  __syncthreads();

  // ---------------- Stage O: out = relu(Wuv @ P + bu), M=512 N=128 K=32 ----------------
  s16x8 bP[8];
#pragma unroll
  for (int ni = 0; ni < 8; ++ni) {
    int p = ni * 16 + i;
    bP[ni] = *(const s16x8*)(P + p * 64 + ((g * 16) ^ ((p & 3) << 4)));
  }
  const short* Wn = WuL + (size_t)n * 16384;
  float* op = out + (size_t)n * CIN * HW + l0;
  // wave-private bounce tile [16 rows][67 f32] (268B rows), reused per 64-px half:
  // 2-way write, 2-way read; dwordx4 stores, 512 B segments per (block, ch-row).
  float* Tb = (float*)(smem + 8192 + w * 4352);   // 8 waves -> 8192+34816 <= 65536
#pragma unroll
  for (int mi = 0; mi < 4; ++mi) {
    int row0 = w * 64 + mi * 16;
    s16x8 aU = *(const s16x8*)(Wn + ((w * 4 + mi) << 9) + (lane << 3));
    f32x4 bias = *(const f32x4*)(bu + row0 + g * 4);
#pragma unroll
    for (int nh = 0; nh < 2; ++nh) {
#pragma unroll
      for (int nl = 0; nl < 4; ++nl) {
        f32x4 o4 = __builtin_amdgcn_mfma_f32_16x16x32_bf16(aU, bP[nh * 4 + nl], bias, 0, 0, 0);
#pragma unroll
        for (int r = 0; r < 4; ++r)
          Tb[(g * 4 + r) * 67 + nl * 16 + i] = fmaxf(o4[r], 0.f);
      }
      // same-wave transposed read-back (compiler inserts lgkmcnt), dwordx4 store
#pragma unroll
      for (int j = 0; j < 4; ++j) {
        int rowr = j * 4 + g;
        f32x4 v = *(const f32x4*)(Tb + rowr * 67 + i * 4);
        *(f32x4*)(op + (size_t)(row0 + rowr) * HW + nh * 64 + i * 4) = v;
      }
    }
  }
}

extern "C" void kernel_launch(void* const* d_in, const int* in_sizes, int n_in,
                              void* d_out, int out_size, void* d_ws, size_t ws_size,
                              hipStream_t stream) {
  (void)in_sizes; (void)n_in; (void)out_size; (void)ws_size;
  const float* x     = (const float*)d_in[0];
  const float* proxy = (const float*)d_in[1];
  const float* w_p1  = (const float*)d_in[2];
  const float* w_p2  = (const float*)d_in[3];
  const float* w_o1  = (const float*)d_in[4];
  const float* w_o2  = (const float*)d_in[5];
  const float* w_d   = (const float*)d_in[6];
  const float* w_u   = (const float*)d_in[7];
  const float* p1g = (const float*)d_in[8],  *p1b = (const float*)d_in[9];
  const float* p1m = (const float*)d_in[10], *p1v = (const float*)d_in[11];
  const float* p2g = (const float*)d_in[12], *p2b = (const float*)d_in[13];
  const float* p2m = (const float*)d_in[14], *p2v = (const float*)d_in[15];
  const float* o1g = (const float*)d_in[16], *o1b = (const float*)d_in[17];
  const float* o1m = (const float*)d_in[18], *o1v = (const float*)d_in[19];
  const float* o2g = (const float*)d_in[20], *o2b = (const float*)d_in[21];
  const float* o2m = (const float*)d_in[22], *o2v = (const float*)d_in[23];
  const float* dg  = (const float*)d_in[24], *db  = (const float*)d_in[25];
  const float* dm  = (const float*)d_in[26], *dv  = (const float*)d_in[27];
  const float* ug  = (const float*)d_in[28], *ub  = (const float*)d_in[29];
  const float* um  = (const float*)d_in[30], *uv  = (const float*)d_in[31];

  char* ws = (char*)d_ws;
  short* W1L    = (short*)(ws + 0);        // 262144 B
  short* W2L    = (short*)(ws + 262144);   // 131072 B
  short* KmL    = (short*)(ws + 393216);   // 131072 B
  short* WuL    = (short*)(ws + 524288);   // 262144 B
  float* b1     = (float*)(ws + 786432);   // 1024 B
  float* b2     = (float*)(ws + 787456);   // 1024 B
  float* bu     = (float*)(ws + 788480);   // 2048 B
  float* t_o1g  = (float*)(ws + 790528);   // 262144 B  [8][32][256] f32
  float* vmatg  = (float*)(ws + 1052672);  // 262144 B  [8][32][256] f32

  kprepA<<<836, 256, 0, stream>>>(proxy,
                                  w_p1, w_p2, p1g, p1b, p1m, p1v,
                                  p2g, p2b, p2m, p2v, ug, ub, um, uv,
                                  w_o1, w_d, o1g, o1b, o1m, o1v,
                                  dg, db, dm, dv,
                                  W1L, W2L, b1, b2, bu, t_o1g, vmatg);
  kprepB<<<96, 256, 0, stream>>>(w_o2, w_u, o2g, o2b, o2m, o2v, ug, uv,
                                 t_o1g, vmatg, KmL, WuL);
  k_main<<<1024, 512, 0, stream>>>(x, W1L, W2L, KmL, WuL, b1, b2, bu, (float*)d_out);
}

// Round 16
// 161.455 us; speedup vs baseline: 1.4047x; 1.4047x over previous
//
#include <hip/hip_runtime.h>

#define HW     16384
#define CIN    512
#define KCH    256
#define NKEY   19
#define NKP    32
#define NBATCH 8

typedef __attribute__((ext_vector_type(8))) short s16x8;
typedef __attribute__((ext_vector_type(4))) short s16x4;
typedef __attribute__((ext_vector_type(4))) float f32x4;
typedef __attribute__((ext_vector_type(2))) float f32x2;

// HW f32->bf16 (RNE): compiles to v_cvt_pk_bf16_f32 on gfx950
__device__ __forceinline__ short f2bf(float f) {
  __bf16 h = (__bf16)f;
  return __builtin_bit_cast(short, h);
}

// Barrier that does NOT drain vmcnt: lgkmcnt(0) (my ds ops done) + s_barrier.
// In-flight global prefetch loads survive across it (T4).
#define BARRIER_LG() do { \
    asm volatile("s_waitcnt lgkmcnt(0)" ::: "memory"); \
    __builtin_amdgcn_s_barrier(); \
    asm volatile("" ::: "memory"); \
  } while (0)

// ---------------- prep A: fold W1/W2/biases (blocks 0..771); GEMM1/3 (blocks 772+) ----
__global__ __launch_bounds__(256) void kprepA(
    const float* __restrict__ proxy,
    const float* __restrict__ w_p1, const float* __restrict__ w_p2,
    const float* __restrict__ p1g, const float* __restrict__ p1b,
    const float* __restrict__ p1m, const float* __restrict__ p1v,
    const float* __restrict__ p2g, const float* __restrict__ p2b,
    const float* __restrict__ p2m, const float* __restrict__ p2v,
    const float* __restrict__ ug,  const float* __restrict__ ub,
    const float* __restrict__ um,  const float* __restrict__ uvv,
    const float* __restrict__ w_o1, const float* __restrict__ w_d,
    const float* __restrict__ o1g, const float* __restrict__ o1b,
    const float* __restrict__ o1m, const float* __restrict__ o1v,
    const float* __restrict__ dg,  const float* __restrict__ db,
    const float* __restrict__ dm,  const float* __restrict__ dv,
    short* __restrict__ W1L, short* __restrict__ W2L,
    float* __restrict__ b1, float* __restrict__ b2, float* __restrict__ bu,
    float* __restrict__ t_o1g, float* __restrict__ vmatg)
{
  __shared__ char PB[32 * 1024];          // [32key][512c] bf16, byte ^ ((key&7)<<4)
  const int tid = threadIdx.x;
  if (blockIdx.x < 772) {
    int t = blockIdx.x * 256 + tid;
    if (t < 131072) {
      int kf = t >> 13, rem = t & 8191, tt = rem >> 9, e512 = rem & 511;
      int l = e512 >> 3, e = e512 & 7;
      int m = tt * 16 + (l & 15);
      int kcol = kf * 32 + (l >> 4) * 8 + e;
      float inv = p1g[m] * rsqrtf(p1v[m] + 1e-5f);
      W1L[t] = f2bf(inv * w_p1[(size_t)m * CIN + kcol]);
    } else if (t < 196608) {
      int u = t - 131072;
      int kf = u >> 13, rem = u & 8191, tt = rem >> 9, e512 = rem & 511;
      int l = e512 >> 3, e = e512 & 7;
      int m = tt * 16 + (l & 15);
      int kcol = kf * 32 + (l >> 4) * 8 + e;
      float inv = p2g[m] * rsqrtf(p2v[m] + 1e-5f);
      W2L[u] = f2bf(inv * w_p2[(size_t)m * KCH + kcol]);
    } else if (t < 196608 + 256) {
      int o = t - 196608;
      float inv = p1g[o] * rsqrtf(p1v[o] + 1e-5f);
      b1[o] = p1b[o] - p1m[o] * inv;
    } else if (t < 196608 + 512) {
      int o = t - 196608 - 256;
      float inv = p2g[o] * rsqrtf(p2v[o] + 1e-5f);
      b2[o] = p2b[o] - p2m[o] * inv;
    } else if (t < 196608 + 1024) {
      int o = t - 196608 - 512;
      float inv = ug[o] * rsqrtf(uvv[o] + 1e-5f);
      bu[o] = ub[o] - um[o] * inv;
    }
    return;
  }
  int bid = blockIdx.x - 772;            // [0,64)
  int sel = bid >> 5;
  int r5  = bid & 31;
  int n   = r5 >> 2;
  int mbase = (r5 & 3) << 6;

  for (int j = 0; j < 8; ++j) *(s16x8*)(PB + (tid + j * 256) * 16) = (s16x8)0;
  __syncthreads();
  const float* pn = proxy + (size_t)n * CIN * NKEY;
  for (int e = tid; e < CIN * NKEY; e += 256) {
    int c = e / NKEY, k = e - c * NKEY;
    *(short*)(PB + k * 1024 + ((c << 1) ^ ((k & 7) << 4))) = f2bf(pn[e]);
  }
  __syncthreads();

  const int w = tid >> 6, lane = tid & 63, g = lane >> 4, i = lane & 15;
  const float* W  = sel ? w_d : w_o1;
  const float* gg = sel ? dg : o1g;
  const float* bb = sel ? db : o1b;
  const float* mm = sel ? dm : o1m;
  const float* vv = sel ? dv : o1v;
  f32x4 acc2[2];
  acc2[0] = (f32x4)0.f; acc2[1] = (f32x4)0.f;
  const int arow = mbase + w * 16 + i;
#pragma unroll 1
  for (int kf = 0; kf < 16; ++kf) {
    const float* wp = W + (size_t)arow * CIN + kf * 32 + g * 8;
    f32x4 a0 = *(const f32x4*)wp, a1 = *(const f32x4*)(wp + 4);
    s16x8 af;
#pragma unroll
    for (int e = 0; e < 4; ++e) { af[e] = f2bf(a0[e]); af[e + 4] = f2bf(a1[e]); }
#pragma unroll
    for (int nj = 0; nj < 2; ++nj) {
      int key = nj * 16 + i;
      s16x8 bf = *(const s16x8*)(PB + key * 1024 + ((kf * 64 + g * 16) ^ ((key & 7) << 4)));
      acc2[nj] = __builtin_amdgcn_mfma_f32_16x16x32_bf16(af, bf, acc2[nj], 0, 0, 0);
    }
  }
  float* dst = (sel ? vmatg : t_o1g) + (size_t)n * 8192;
#pragma unroll
  for (int r = 0; r < 4; ++r) {
    int o = mbase + w * 16 + g * 4 + r;
    float inv = gg[o] * rsqrtf(vv[o] + 1e-5f);
    float beta = bb[o] - mm[o] * inv;
#pragma unroll
    for (int nj = 0; nj < 2; ++nj) {
      int key = nj * 16 + i;
      dst[key * 256 + o] = fmaxf(acc2[nj][r] * inv + beta, 0.f);
    }
  }
}

// ---------------- prep B: GEMM2 -> KmL (frag layout), GEMM4 -> WuL (frag layout) ------
__global__ __launch_bounds__(256) void kprepB(
    const float* __restrict__ w_o2, const float* __restrict__ w_u,
    const float* __restrict__ o2g, const float* __restrict__ o2b,
    const float* __restrict__ o2m, const float* __restrict__ o2v,
    const float* __restrict__ ug,  const float* __restrict__ uvv,
    const float* __restrict__ t_o1g, const float* __restrict__ vmatg,
    short* __restrict__ KmL, short* __restrict__ WuL)
{
  __shared__ char TB[32 * 512];           // [32key][256o] bf16, byte ^ ((key&7)<<4)
  const int tid = threadIdx.x;
  const int isKm = (blockIdx.x < 32);
  int n, mbase;
  const float* src;
  if (isKm) { n = blockIdx.x >> 2; mbase = (blockIdx.x & 3) << 6; src = t_o1g; }
  else { int b2_ = blockIdx.x - 32; n = b2_ >> 3; mbase = (b2_ & 7) << 6; src = vmatg; }
  const float* sn = src + (size_t)n * 8192;
  for (int j = 0; j < 32; ++j) {
    int idx = tid + j * 256;
    int key = idx >> 8, o = idx & 255;
    *(short*)(TB + key * 512 + ((o << 1) ^ ((key & 7) << 4))) = f2bf(sn[idx]);
  }
  __syncthreads();

  const int w = tid >> 6, lane = tid & 63, g = lane >> 4, i = lane & 15;
  const float* W = isKm ? w_o2 : w_u;
  f32x4 acc2[2];
  acc2[0] = (f32x4)0.f; acc2[1] = (f32x4)0.f;
  const int arow = mbase + w * 16 + i;
#pragma unroll 1
  for (int kf = 0; kf < 8; ++kf) {
    const float* wp = W + (size_t)arow * KCH + kf * 32 + g * 8;
    f32x4 a0 = *(const f32x4*)wp, a1 = *(const f32x4*)(wp + 4);
    s16x8 af;
#pragma unroll
    for (int e = 0; e < 4; ++e) { af[e] = f2bf(a0[e]); af[e + 4] = f2bf(a1[e]); }
#pragma unroll
    for (int nj = 0; nj < 2; ++nj) {
      int key = nj * 16 + i;
      s16x8 bf = *(const s16x8*)(TB + key * 512 + ((kf * 64 + g * 16) ^ ((key & 7) << 4)));
      acc2[nj] = __builtin_amdgcn_mfma_f32_16x16x32_bf16(af, bf, acc2[nj], 0, 0, 0);
    }
  }
  if (isKm) {
    short* Kn = KmL + (size_t)n * 8192;
#pragma unroll
    for (int r = 0; r < 4; ++r) {
      int o2 = mbase + w * 16 + g * 4 + r;
      float inv = o2g[o2] * rsqrtf(o2v[o2] + 1e-5f);
      float beta = o2b[o2] - o2m[o2] * inv;
#pragma unroll
      for (int nj = 0; nj < 2; ++nj) {
        float val = fmaxf(acc2[nj][r] * inv + beta, 0.f) * 0.0625f;
        Kn[((o2 >> 5) * 2 + nj) * 512 + (((o2 >> 3) & 3) * 16 + i) * 8 + (o2 & 7)] = f2bf(val);
      }
    }
  } else {
    short* Wn = WuL + (size_t)n * 16384;
#pragma unroll
    for (int r = 0; r < 4; ++r) {
      int c = mbase + w * 16 + g * 4 + r;
      float inv = ug[c] * rsqrtf(uvv[c] + 1e-5f);
#pragma unroll
      for (int nj = 0; nj < 2; ++nj) {
        int key = nj * 16 + i;
        float val = acc2[nj][r] * inv;
        Wn[(c >> 4) * 512 + ((key >> 3) * 16 + (c & 15)) * 8 + (key & 7)] = f2bf(val);
      }
    }
  }
}

// ---------------- fused main kernel: 256 threads / 64 pixels / 32 KB LDS --------------
// Stage A staging: thread owns 2 px x 8 ch (2-way-free banks on write & read). Ring-3,
// 2-chunk-ahead prefetch. Loop barriers are BARRIER_LG (lgkmcnt-only) so the
// prefetch loads stay in flight across barriers (T4: never vmcnt(0) in the loop).
#define LOADCHUNK(R2, ck) do { \
    const float* xp = xb2 + (size_t)((ck) * 64 + ch0) * HW; \
    _Pragma("unroll") \
    for (int c = 0; c < 8; ++c) (R2)[c] = *(const f32x2*)(xp + (size_t)c * HW); \
  } while (0)

#define WRITECHUNK(R2, ck) do { \
    char* wr_ = smem + ((ck) % 3) * 8192; \
    _Pragma("unroll") \
    for (int p = 0; p < 2; ++p) { \
      int px_ = pxp + p; \
      s16x8 h; \
      _Pragma("unroll") \
      for (int c = 0; c < 8; ++c) h[c] = f2bf((R2)[c][p]); \
      *(s16x8*)(wr_ + px_ * 128 + ((ch0 << 1) ^ ((px_ & 7) << 4))) = h; \
    } \
  } while (0)

#define MFMASTEP(ck) do { \
    const char* rb_ = smem + ((ck) % 3) * 8192; \
    _Pragma("unroll") \
    for (int ks = 0; ks < 2; ++ks) { \
      s16x8 af[4], bf[4]; \
      _Pragma("unroll") \
      for (int mi = 0; mi < 4; ++mi) \
        af[mi] = *(const s16x8*)(W1L + ((((ck) * 2 + ks) * 16 + (w * 4 + mi)) << 9) + (lane << 3)); \
      _Pragma("unroll") \
      for (int ni = 0; ni < 4; ++ni) { \
        int p_ = ni * 16 + i; \
        bf[ni] = *(const s16x8*)(rb_ + p_ * 128 + (((ks * 32 + g * 8) << 1) ^ ((p_ & 7) << 4))); \
      } \
      _Pragma("unroll") \
      for (int mi = 0; mi < 4; ++mi) \
        _Pragma("unroll") \
        for (int ni = 0; ni < 4; ++ni) \
          acc[mi][ni] = __builtin_amdgcn_mfma_f32_16x16x32_bf16(af[mi], bf[ni], acc[mi][ni], 0, 0, 0); \
    } \
  } while (0)

__global__ __launch_bounds__(256, 4) void k_main(
    const float* __restrict__ x,
    const short* __restrict__ W1L, const short* __restrict__ W2L,
    const short* __restrict__ KmL, const short* __restrict__ WuL,
    const float* __restrict__ b1, const float* __restrict__ b2,
    const float* __restrict__ bu,
    float* __restrict__ out)
{
  __shared__ char smem[32768];
  char* t1q = smem;

  const int tid  = threadIdx.x;
  const int w    = tid >> 6;     // wave 0..3
  const int lane = tid & 63;
  const int g    = lane >> 4;
  const int i    = lane & 15;
  const int n    = blockIdx.x >> 8;
  const int l0   = (blockIdx.x & 255) << 6;

  f32x4 acc[4][4];
#pragma unroll
  for (int a_ = 0; a_ < 4; ++a_)
#pragma unroll
    for (int b_ = 0; b_ < 4; ++b_) acc[a_][b_] = (f32x4)0.f;

  // ---------------- Stage A: t1 = relu(W1' @ x + b1), M=256 N=64 K=512 -----------------
  const int pxp = (lane & 31) << 1;              // px pair base 0..62
  const int ch0 = (((lane >> 5) + (w << 1)) << 3); // ch octet base within chunk
  const float* xb2 = x + (size_t)n * CIN * HW + l0 + pxp;

  f32x2 RA[8], RB[8];
  LOADCHUNK(RA, 0);
  LOADCHUNK(RB, 1);
  WRITECHUNK(RA, 0);
  BARRIER_LG();

#pragma unroll
  for (int cp = 0; cp < 4; ++cp) {
    const int cka = 2 * cp, ckb = 2 * cp + 1;
    if (cka + 2 < 8) LOADCHUNK(RA, cka + 2);   // issue loads 2 chunks ahead
    WRITECHUNK(RB, ckb);                        // write chunk loaded last iter
    MFMASTEP(cka);
    BARRIER_LG();
    if (ckb + 2 < 8) LOADCHUNK(RB, ckb + 2);
    if (ckb + 1 < 8) WRITECHUNK(RA, ckb + 1);
    MFMASTEP(ckb);
    BARRIER_LG();
  }

  // epilogue A -> t1q (ring dead; all LDS reads drained at the loop's final barrier)
#pragma unroll
  for (int mi = 0; mi < 4; ++mi) {
    f32x4 bias = *(const f32x4*)(b1 + w * 64 + mi * 16 + g * 4);
#pragma unroll
    for (int ni = 0; ni < 4; ++ni) {
      int p = ni * 16 + i;
      s16x4 hh;
#pragma unroll
      for (int r = 0; r < 4; ++r) hh[r] = f2bf(fmaxf(acc[mi][ni][r] + bias[r], 0.f));
      *(s16x4*)(t1q + p * 512 + (((w * 64 + mi * 16 + g * 4) << 1) ^ ((p & 7) << 4))) = hh;
      acc[mi][ni] = (f32x4)0.f;
    }
  }
  __syncthreads();

  // ---------------- Stage B: q = relu(W2' @ t1 + b2), M=256 N=64 K=256 -----------------
#pragma unroll 2
  for (int ks = 0; ks < 8; ++ks) {
    s16x8 af[4], bf[4];
#pragma unroll
    for (int mi = 0; mi < 4; ++mi)
      af[mi] = *(const s16x8*)(W2L + (((ks * 16) + (w * 4 + mi)) << 9) + (lane << 3));
#pragma unroll
    for (int ni = 0; ni < 4; ++ni) {
      int p = ni * 16 + i;
      bf[ni] = *(const s16x8*)(t1q + p * 512 + (((ks * 32 + g * 8) << 1) ^ ((p & 7) << 4)));
    }
#pragma unroll
    for (int mi = 0; mi < 4; ++mi)
#pragma unroll
      for (int ni = 0; ni < 4; ++ni)
        acc[mi][ni] = __builtin_amdgcn_mfma_f32_16x16x32_bf16(af[mi], bf[ni], acc[mi][ni], 0, 0, 0);
  }
  __syncthreads();              // all t1 reads complete before overwrite
#pragma unroll
  for (int mi = 0; mi < 4; ++mi) {
    f32x4 bias = *(const f32x4*)(b2 + w * 64 + mi * 16 + g * 4);
#pragma unroll
    for (int ni = 0; ni < 4; ++ni) {
      int p = ni * 16 + i;
      s16x4 hh;
#pragma unroll
      for (int r = 0; r < 4; ++r) hh[r] = f2bf(fmaxf(acc[mi][ni][r] + bias[r], 0.f));
      *(s16x4*)(t1q + p * 512 + (((w * 64 + mi * 16 + g * 4) << 1) ^ ((p & 7) << 4))) = hh;
    }
  }
  __syncthreads();

  // ---------------- Stage S: simT = K_scaled @ q, softmax over k<19 --------------------
  f32x4 as_[2];
  as_[0] = (f32x4)0.f; as_[1] = (f32x4)0.f;
  const short* Kn = KmL + (size_t)n * 8192;
  const int ps = (w << 4) | i;          // this lane's pixel 0..63
  const int psw = (ps & 7) << 4;
#pragma unroll
  for (int ks = 0; ks < 8; ++ks) {
    s16x8 bq = *(const s16x8*)(t1q + ps * 512 + (((ks * 32 + g * 8) << 1) ^ psw));
#pragma unroll
    for (int mi = 0; mi < 2; ++mi) {
      s16x8 ak = *(const s16x8*)(Kn + (((ks * 2 + mi)) << 9) + (lane << 3));
      as_[mi] = __builtin_amdgcn_mfma_f32_16x16x32_bf16(ak, bq, as_[mi], 0, 0, 0);
    }
  }
  float mx = -1e30f;
#pragma unroll
  for (int mi = 0; mi < 2; ++mi)
#pragma unroll
    for (int r = 0; r < 4; ++r) {
      int k = mi * 16 + g * 4 + r;
      if (k < NKEY) mx = fmaxf(mx, as_[mi][r]);
    }
  mx = fmaxf(mx, __shfl_xor(mx, 16, 64));
  mx = fmaxf(mx, __shfl_xor(mx, 32, 64));
  float e[2][4];
  float sum = 0.f;
#pragma unroll
  for (int mi = 0; mi < 2; ++mi)
#pragma unroll
    for (int r = 0; r < 4; ++r) {
      int k = mi * 16 + g * 4 + r;
      float t = (k < NKEY) ? __expf(as_[mi][r] - mx) : 0.f;
      e[mi][r] = t;
      sum += t;
    }
  sum += __shfl_xor(sum, 16, 64);
  sum += __shfl_xor(sum, 32, 64);
  float rs = 1.f / sum;
  __syncthreads();                      // all t1q reads done before P overwrites it
  char* P = smem;                       // [64p][32k] bf16, swizzle (p&3)<<4
#pragma unroll
  for (int mi = 0; mi < 2; ++mi) {
    s16x4 hh;
#pragma unroll
    for (int r = 0; r < 4; ++r) hh[r] = f2bf(e[mi][r] * rs);
    *(s16x4*)(P + ps * 64 + (((mi * 16 + g * 4) << 1) ^ ((ps & 3) << 4))) = hh;
  }
  __syncthreads();

  // ---------------- Stage O: out = relu(Wuv @ P + bu), M=512 N=64 K=32 -----------------
  s16x8 bP[4];
#pragma unroll
  for (int ni = 0; ni < 4; ++ni) {
    int p = ni * 16 + i;
    bP[ni] = *(const s16x8*)(P + p * 64 + ((g * 16) ^ ((p & 3) << 4)));
  }
  const short* Wn = WuL + (size_t)n * 16384;
  float* op = out + (size_t)n * CIN * HW + l0;
  // wave-private bounce tile [16 rows][67 f32] (268B rows): 2-way write, 2-way read;
  // enables dwordx4 stores (256B segments).
  float* Tb = (float*)(smem + 8192 + w * 4352);
#pragma unroll
  for (int mi = 0; mi < 8; ++mi) {
    int row0 = w * 128 + mi * 16;
    s16x8 aU = *(const s16x8*)(Wn + ((w * 8 + mi) << 9) + (lane << 3));
    f32x4 bias = *(const f32x4*)(bu + row0 + g * 4);
#pragma unroll
    for (int ni = 0; ni < 4; ++ni) {
      f32x4 o4 = __builtin_amdgcn_mfma_f32_16x16x32_bf16(aU, bP[ni], bias, 0, 0, 0);
#pragma unroll
      for (int r = 0; r < 4; ++r)
        Tb[(g * 4 + r) * 67 + ni * 16 + i] = fmaxf(o4[r], 0.f);
    }
    // same-wave transposed read-back (compiler inserts lgkmcnt), dwordx4 store
#pragma unroll
    for (int j = 0; j < 4; ++j) {
      int rowr = j * 4 + g;
      f32x4 v = *(const f32x4*)(Tb + rowr * 67 + i * 4);
      *(f32x4*)(op + (size_t)(row0 + rowr) * HW + i * 4) = v;
    }
  }
}

extern "C" void kernel_launch(void* const* d_in, const int* in_sizes, int n_in,
                              void* d_out, int out_size, void* d_ws, size_t ws_size,
                              hipStream_t stream) {
  (void)in_sizes; (void)n_in; (void)out_size; (void)ws_size;
  const float* x     = (const float*)d_in[0];
  const float* proxy = (const float*)d_in[1];
  const float* w_p1  = (const float*)d_in[2];
  const float* w_p2  = (const float*)d_in[3];
  const float* w_o1  = (const float*)d_in[4];
  const float* w_o2  = (const float*)d_in[5];
  const float* w_d   = (const float*)d_in[6];
  const float* w_u   = (const float*)d_in[7];
  const float* p1g = (const float*)d_in[8],  *p1b = (const float*)d_in[9];
  const float* p1m = (const float*)d_in[10], *p1v = (const float*)d_in[11];
  const float* p2g = (const float*)d_in[12], *p2b = (const float*)d_in[13];
  const float* p2m = (const float*)d_in[14], *p2v = (const float*)d_in[15];
  const float* o1g = (const float*)d_in[16], *o1b = (const float*)d_in[17];
  const float* o1m = (const float*)d_in[18], *o1v = (const float*)d_in[19];
  const float* o2g = (const float*)d_in[20], *o2b = (const float*)d_in[21];
  const float* o2m = (const float*)d_in[22], *o2v = (const float*)d_in[23];
  const float* dg  = (const float*)d_in[24], *db  = (const float*)d_in[25];
  const float* dm  = (const float*)d_in[26], *dv  = (const float*)d_in[27];
  const float* ug  = (const float*)d_in[28], *ub  = (const float*)d_in[29];
  const float* um  = (const float*)d_in[30], *uv  = (const float*)d_in[31];

  char* ws = (char*)d_ws;
  short* W1L    = (short*)(ws + 0);        // 262144 B
  short* W2L    = (short*)(ws + 262144);   // 131072 B
  short* KmL    = (short*)(ws + 393216);   // 131072 B
  short* WuL    = (short*)(ws + 524288);   // 262144 B
  float* b1     = (float*)(ws + 786432);   // 1024 B
  float* b2     = (float*)(ws + 787456);   // 1024 B
  float* bu     = (float*)(ws + 788480);   // 2048 B
  float* t_o1g  = (float*)(ws + 790528);   // 262144 B  [8][32][256] f32
  float* vmatg  = (float*)(ws + 1052672);  // 262144 B  [8][32][256] f32

  kprepA<<<836, 256, 0, stream>>>(proxy,
                                  w_p1, w_p2, p1g, p1b, p1m, p1v,
                                  p2g, p2b, p2m, p2v, ug, ub, um, uv,
                                  w_o1, w_d, o1g, o1b, o1m, o1v,
                                  dg, db, dm, dv,
                                  W1L, W2L, b1, b2, bu, t_o1g, vmatg);
  kprepB<<<96, 256, 0, stream>>>(w_o2, w_u, o2g, o2b, o2m, o2v, ug, uv,
                                 t_o1g, vmatg, KmL, WuL);
  k_main<<<2048, 256, 0, stream>>>(x, W1L, W2L, KmL, WuL, b1, b2, bu, (float*)d_out);
}